// Round 4
// baseline (23405.417 us; speedup 1.0000x reference)
//
#include <hip/hip_runtime.h>
#include <stdint.h>
#include <math.h>

// Decoder: autoregressive GRU (B=128,H=512,T=256) -> LSTM (L=1024) -> FC (V=1024)
// *** fp32 I/O *** (reference dtypes are float32). Internal math fp32; GEMMs via
// MFMA 16x16x32 bf16 with split-bf16 (hi/lo) weights AND activations (w = wh+wl
// to ~2^-17), 3-pass MFMA per pair. Weights converted fp32->hi/lo once per block
// at LDS staging. seq (relu(x_t), bf16 hi/lo planes) is packed inside d_out's
// fp32 slots and consumed one barrier generation before logits overwrite it.
// Workspace use: 1.58 MB (proven available in round 3).

typedef unsigned short u16;
typedef unsigned int u32;
typedef __attribute__((ext_vector_type(8))) short short8;   // 8 bf16 = 4 VGPR
typedef __attribute__((ext_vector_type(4))) float float4_;  // MFMA acc

#define MFMA(a, b, c) __builtin_amdgcn_mfma_f32_16x16x32_bf16((a), (b), (c), 0, 0, 0)

__device__ __forceinline__ float bf2f(u16 u) {
  union { u32 i; float f; } v; v.i = ((u32)u) << 16; return v.f;
}
__device__ __forceinline__ u16 f2bf(float f) {
  union { float f; u32 i; } v; v.f = f;
  u32 x = v.i;
  return (u16)((x + 0x7fffu + ((x >> 16) & 1u)) >> 16);  // RNE, finite inputs only
}
__device__ __forceinline__ void split2(float w, u16& h, u16& l) {
  h = f2bf(w); l = f2bf(w - bf2f(h));
}
__device__ __forceinline__ float sigm(float x) { return 1.0f / (1.0f + expf(-x)); }

// Build bf16 hi/lo A-fragments from 8 consecutive fp32 values.
__device__ __forceinline__ void frag_from_f32(const float* p, short8& hi, short8& lo) {
  short8 h, l;
#pragma unroll
  for (int j = 0; j < 8; ++j) {
    u16 a, b; split2(p[j], a, b);
    h[j] = (short)a; l[j] = (short)b;
  }
  hi = h; lo = l;
}

// Device-scope grid barrier (monotone counter; cross-XCD fences via threadfence).
__device__ __forceinline__ void grid_barrier(u32* bar, u32 gen, u32 nblk) {
  __syncthreads();
  if (threadIdx.x == 0) {
    __threadfence();                 // release
    atomicAdd(bar, 1u);
    const u32 target = gen * nblk;
    while (__hip_atomic_load(bar, __ATOMIC_RELAXED, __HIP_MEMORY_SCOPE_AGENT) < target)
      __builtin_amdgcn_s_sleep(2);
  }
  __syncthreads();
  __threadfence();                   // acquire
}

// ---------------------------------------------------------------------------
// Kernel 1: persistent GRU chain. 128 blocks x 256 threads.
// Block = (batch half: 64 rows) x (8 hidden cols); 3 B-tiles {Wih_g|Whh_g},
// g in {r,z,n}, weights hi/lo in LDS. x broadcast via ws hi/lo ping-pong.
// seq (relu x_t) -> bf16 hi/lo planes packed into out[b][t] fp32 slots:
// u16 index k = hi, 512+k = lo (k < 512). seq[0] is never read.
// ---------------------------------------------------------------------------
__global__ __launch_bounds__(256)
void gru_chain(const float* __restrict__ z,
               const float* __restrict__ Wih, const float* __restrict__ Whh,
               const float* __restrict__ bih, const float* __restrict__ bhh,
               u16* outu, u16* __restrict__ xpp, u32* bar) {
  __shared__ __align__(16) u16 wh_lds[48 * 520];
  __shared__ __align__(16) u16 wl_lds[48 * 520];
  __shared__ float blds[32];  // [0:8)=r bias sum, [8:16)=z sum, [16:24)=bih_n, [24:32)=bhh_n

  const int tid = threadIdx.x;
  const int wg = blockIdx.x;
  const int grp = wg & 63;       // column group (8 cols)
  const int mhalf = wg >> 6;     // batch half
  const int jb = grp * 8;

  // stage + convert weight slice: rows 0..47 = tile*16 + n; n<8 -> Wih, n>=8 -> Whh
  for (int idx = tid; idx < 48 * 512; idx += 256) {
    int row = idx >> 9, k = idx & 511;
    int t3 = row >> 4, n = row & 15;
    int grow = t3 * 512 + jb + (n & 7);
    float w = ((n < 8) ? Wih : Whh)[(size_t)grow * 512 + k];
    u16 h, l; split2(w, h, l);
    wh_lds[row * 520 + k] = h;
    wl_lds[row * 520 + k] = l;
  }
  if (tid < 8) {
    blds[tid]      = bih[jb + tid] + bhh[jb + tid];
    blds[8 + tid]  = bih[512 + jb + tid] + bhh[512 + jb + tid];
    blds[16 + tid] = bih[1024 + jb + tid];
    blds[24 + tid] = bhh[1024 + jb + tid];
  }
  __syncthreads();

  const int lane = tid & 63, wv = tid >> 6;
  const int n16 = lane & 15, q = lane >> 4;
  const int j8 = n16 & 7;
  const int mrow = mhalf * 64 + wv * 16 + n16;      // A-frag row
  const int orow0 = mhalf * 64 + wv * 16 + q * 4;   // D rows base
  const bool act = (n16 < 8);
  const int col = jb + j8;

  float x_own[4];  // this lane's x values (fp32, persists across steps)

  // ---- step 1: x1 = GRU(x=0, h=z); A = z hi/lo ----
  {
    float4_ acc0 = {0.f, 0.f, 0.f, 0.f}, acc1 = acc0, acc2 = acc0;
    for (int ki = 0; ki < 16; ++ki) {
      const int ko = ki * 32 + q * 8;
      short8 ah, al;
      frag_from_f32(z + (size_t)mrow * 512 + ko, ah, al);
      short8 b0h = *(const short8*)(wh_lds + (0 * 16 + n16) * 520 + ko);
      short8 b1h = *(const short8*)(wh_lds + (1 * 16 + n16) * 520 + ko);
      short8 b2h = *(const short8*)(wh_lds + (2 * 16 + n16) * 520 + ko);
      short8 b0l = *(const short8*)(wl_lds + (0 * 16 + n16) * 520 + ko);
      short8 b1l = *(const short8*)(wl_lds + (1 * 16 + n16) * 520 + ko);
      short8 b2l = *(const short8*)(wl_lds + (2 * 16 + n16) * 520 + ko);
      acc0 = MFMA(ah, b0h, acc0); acc0 = MFMA(al, b0h, acc0); acc0 = MFMA(ah, b0l, acc0);
      acc1 = MFMA(ah, b1h, acc1); acc1 = MFMA(al, b1h, acc1); acc1 = MFMA(ah, b1l, acc1);
      acc2 = MFMA(ah, b2h, acc2); acc2 = MFMA(al, b2h, acc2); acc2 = MFMA(ah, b2l, acc2);
    }
    for (int reg = 0; reg < 4; ++reg) {
      float pr = __shfl_xor(acc0[reg], 8);   // z@Whh_r (from partner lane n+8)
      float pz = __shfl_xor(acc1[reg], 8);
      float pn = __shfl_xor(acc2[reg], 8);
      float r  = sigm(pr + blds[j8]);                       // gi = bih only (x=0)
      float zg = sigm(pz + blds[8 + j8]);
      float nn = tanhf(blds[16 + j8] + r * (pn + blds[24 + j8]));
      float hv = act ? z[(size_t)(orow0 + reg) * 512 + col] : 0.f;  // h0 = z
      float xn = (1.f - zg) * nn + zg * hv;
      x_own[reg] = xn;
      if (act) {
        size_t po = (size_t)(orow0 + reg) * 512 + col;
        u16 h, l; split2(xn, h, l);
        xpp[(size_t)2 * 65536 + po] = h;   // slot 1, hi plane
        xpp[(size_t)3 * 65536 + po] = l;   // slot 1, lo plane
        float rl = fmaxf(xn, 0.f);
        u16 rh, rlo; split2(rl, rh, rlo);
        size_t so = ((size_t)(orow0 + reg) * 256 + 1) * 2048;  // out[b][1] as u16
        outu[so + col] = rh;
        outu[so + 512 + col] = rlo;
      }
    }
  }
  grid_barrier(bar, 1, 128);

  // ---- steps 2..255: x==h, A = x_{t-1} hi/lo ----
  for (int t = 2; t < 256; ++t) {
    const int sr = (t - 1) & 1, sw = t & 1;
    const u16* xh = xpp + (size_t)(sr * 2 + 0) * 65536 + (size_t)mrow * 512;
    const u16* xl = xpp + (size_t)(sr * 2 + 1) * 65536 + (size_t)mrow * 512;
    float4_ acc0 = {0.f, 0.f, 0.f, 0.f}, acc1 = acc0, acc2 = acc0;
    for (int ki = 0; ki < 16; ++ki) {
      const int ko = ki * 32 + q * 8;
      short8 ah = *(const short8*)(xh + ko);
      short8 al = *(const short8*)(xl + ko);
      short8 b0h = *(const short8*)(wh_lds + (0 * 16 + n16) * 520 + ko);
      short8 b1h = *(const short8*)(wh_lds + (1 * 16 + n16) * 520 + ko);
      short8 b2h = *(const short8*)(wh_lds + (2 * 16 + n16) * 520 + ko);
      short8 b0l = *(const short8*)(wl_lds + (0 * 16 + n16) * 520 + ko);
      short8 b1l = *(const short8*)(wl_lds + (1 * 16 + n16) * 520 + ko);
      short8 b2l = *(const short8*)(wl_lds + (2 * 16 + n16) * 520 + ko);
      acc0 = MFMA(ah, b0h, acc0); acc0 = MFMA(al, b0h, acc0); acc0 = MFMA(ah, b0l, acc0);
      acc1 = MFMA(ah, b1h, acc1); acc1 = MFMA(al, b1h, acc1); acc1 = MFMA(ah, b1l, acc1);
      acc2 = MFMA(ah, b2h, acc2); acc2 = MFMA(al, b2h, acc2); acc2 = MFMA(ah, b2l, acc2);
    }
    for (int reg = 0; reg < 4; ++reg) {
      float ar = acc0[reg], az = acc1[reg], an = acc2[reg];
      float pr = __shfl_xor(ar, 8), pz = __shfl_xor(az, 8), pn = __shfl_xor(an, 8);
      float r  = sigm(ar + pr + blds[j8]);
      float zg = sigm(az + pz + blds[8 + j8]);
      float nn = tanhf(an + blds[16 + j8] + r * (pn + blds[24 + j8]));
      float xn = (1.f - zg) * nn + zg * x_own[reg];
      x_own[reg] = xn;
      if (act) {
        size_t po = (size_t)(orow0 + reg) * 512 + col;
        u16 h, l; split2(xn, h, l);
        xpp[(size_t)(sw * 2 + 0) * 65536 + po] = h;
        xpp[(size_t)(sw * 2 + 1) * 65536 + po] = l;
        float rl = fmaxf(xn, 0.f);
        u16 rh, rlo; split2(rl, rh, rlo);
        size_t so = ((size_t)(orow0 + reg) * 256 + t) * 2048;
        outu[so + col] = rh;
        outu[so + 512 + col] = rlo;
      }
    }
    if (t < 255) grid_barrier(bar, t, 128);
  }
}

// ---------------------------------------------------------------------------
// Kernel 2: persistent LSTM chain with fused FC. 256 blocks x 512 threads.
// Block s: LSTM cols = s*4..s*4+3 (one 16-gate-col B-tile {i,f,g,o}x4, hi/lo
// Whh + Wih in LDS, ~100 KB); batch = all 128 rows (8 waves = 8 m-tiles).
// FC: vtile = s&63 (16 v-cols), batch-quarter bq = s>>6 (32 rows), full K=1024
// split 4-way across waves, reduced in LDS, plain fp32 stores (no atomics);
// logits_{t-1} overwrite out[b][t-1] AFTER barrier t (seq[t-1] consumed at
// step t-1 before barrier t => race-free). h recurrence: ws hi/lo ping-pong.
// ---------------------------------------------------------------------------
__global__ __launch_bounds__(512)
void lstm_fc_chain(const float* __restrict__ Wih, const float* __restrict__ Whh,
                   const float* __restrict__ bih, const float* __restrict__ bhh,
                   const float* __restrict__ fcW, const float* __restrict__ fcb,
                   u16* __restrict__ hpp, u16* outu, float* outf, u32* bar) {
  __shared__ __align__(16) u16 whh_hi[16 * 1032];
  __shared__ __align__(16) u16 whh_lo[16 * 1032];
  __shared__ __align__(16) u16 wih_hi[16 * 520];
  __shared__ __align__(16) u16 wih_lo[16 * 520];
  __shared__ float glds[128][17];        // gate preacts [b][gatecol]
  __shared__ float pglds[2][16][4][16];  // FC partials [mt][row][kq][vcol]
  __shared__ float bclds[16];            // combined lstm biases (16 gate-cols)
  __shared__ float fclds[16];            // fc bias slice

  const int tid = threadIdx.x;
  const int s = blockIdx.x;
  const int colbase = s * 4;             // 4 LSTM h-cols
  const int vt = s & 63, bq = s >> 6;    // FC: v-tile and batch-quarter
  const int vbase = vt * 16;

  // stage + convert Whh rows (16 gate-cols x 1024) and Wih rows (x 512)
  for (int idx = tid; idx < 16 * 1024; idx += 512) {
    int row = idx >> 10, k = idx & 1023;
    int gate = row >> 2, cc = row & 3;
    float w = Whh[(size_t)(gate * 1024 + colbase + cc) * 1024 + k];
    u16 h, l; split2(w, h, l);
    whh_hi[row * 1032 + k] = h;
    whh_lo[row * 1032 + k] = l;
  }
  for (int idx = tid; idx < 16 * 512; idx += 512) {
    int row = idx >> 9, k = idx & 511;
    int gate = row >> 2, cc = row & 3;
    float w = Wih[(size_t)(gate * 1024 + colbase + cc) * 512 + k];
    u16 h, l; split2(w, h, l);
    wih_hi[row * 520 + k] = h;
    wih_lo[row * 520 + k] = l;
  }
  if (tid < 16) {
    int gate = tid >> 2, cc = tid & 3;
    int wcol = gate * 1024 + colbase + cc;
    bclds[tid] = bih[wcol] + bhh[wcol];
    fclds[tid] = fcb[vbase + tid];
  }
  __syncthreads();

  const int lane = tid & 63, wv = tid >> 6;   // wv = m-tile (batch/16)
  const int n16 = lane & 15, q = lane >> 4;
  const int arow = wv * 16 + n16;             // LSTM A-frag batch row
  const int myrow = tid >> 2, mycol = tid & 3;   // cell (b, local h-col)
  // FC wave roles: mt = m-tile within batch-quarter, kq = K-quarter
  const int fmt = wv & 1, fkq = wv >> 1;
  const int frow = bq * 32 + fmt * 16 + n16;  // FC A-frag batch row
  const int fkbase = fkq * 256;

  // fcW fragments (vtile rows, this wave's K-quarter) -> registers, hi/lo
  short8 brh[8], brl[8];
  for (int i = 0; i < 8; ++i)
    frag_from_f32(fcW + (size_t)(vbase + n16) * 1024 + fkbase + i * 32 + q * 8,
                  brh[i], brl[i]);

  float c = 0.f;

  // t = 0: h_prev = 0, seq[0] = 0 -> preacts are just biases
  {
    float pi = bclds[mycol], pg = bclds[8 + mycol], po = bclds[12 + mycol];
    c = sigm(pi) * tanhf(pg);
    float h = sigm(po) * tanhf(c);
    size_t off = (size_t)myrow * 1024 + colbase + mycol;
    u16 hh, hl; split2(h, hh, hl);
    hpp[off] = hh;               // slot 0 hi
    hpp[131072 + off] = hl;      // slot 0 lo
  }
  grid_barrier(bar, 1, 256);

  for (int t = 1; t < 256; ++t) {
    const int sr = (t - 1) & 1, sw = t & 1;
    const u16* ph = hpp + (size_t)(sr * 2 + 0) * 131072 + (size_t)arow * 1024;
    const u16* pl = hpp + (size_t)(sr * 2 + 1) * 131072 + (size_t)arow * 1024;
    float4_ acc = {0.f, 0.f, 0.f, 0.f};
    for (int ki = 0; ki < 32; ++ki) {        // recurrent: K=1024, 3-pass
      const int ko = ki * 32 + q * 8;
      short8 ah = *(const short8*)(ph + ko);
      short8 al = *(const short8*)(pl + ko);
      short8 bh = *(const short8*)(whh_hi + n16 * 1032 + ko);
      short8 bl = *(const short8*)(whh_lo + n16 * 1032 + ko);
      acc = MFMA(ah, bh, acc); acc = MFMA(al, bh, acc); acc = MFMA(ah, bl, acc);
    }
    {
      const u16* sq = outu + ((size_t)arow * 256 + t) * 2048;  // seq[t] planes
      for (int ki = 0; ki < 16; ++ki) {      // input: K=512, 3-pass
        const int ko = ki * 32 + q * 8;
        short8 sh = *(const short8*)(sq + ko);
        short8 sl = *(const short8*)(sq + 512 + ko);
        short8 bh = *(const short8*)(wih_hi + n16 * 520 + ko);
        short8 bl = *(const short8*)(wih_lo + n16 * 520 + ko);
        acc = MFMA(sh, bh, acc); acc = MFMA(sl, bh, acc); acc = MFMA(sh, bl, acc);
      }
    }
    for (int reg = 0; reg < 4; ++reg)
      glds[wv * 16 + q * 4 + reg][n16] = acc[reg];
    __syncthreads();
    {
      float pi = glds[myrow][mycol]      + bclds[mycol];
      float pf = glds[myrow][4 + mycol]  + bclds[4 + mycol];
      float pg = glds[myrow][8 + mycol]  + bclds[8 + mycol];
      float po = glds[myrow][12 + mycol] + bclds[12 + mycol];
      c = sigm(pf) * c + sigm(pi) * tanhf(pg);
      float h = sigm(po) * tanhf(c);
      size_t off = (size_t)myrow * 1024 + colbase + mycol;
      u16 hh, hl; split2(h, hh, hl);
      hpp[(size_t)(sw * 2 + 0) * 131072 + off] = hh;
      hpp[(size_t)(sw * 2 + 1) * 131072 + off] = hl;
    }

    // fused FC: logits_{t-1} = h_{t-1} @ fcW^T + fcb (wave K-quarter partials)
    {
      const u16* fh = hpp + (size_t)(sr * 2 + 0) * 131072 + (size_t)frow * 1024 + fkbase;
      const u16* fl = hpp + (size_t)(sr * 2 + 1) * 131072 + (size_t)frow * 1024 + fkbase;
      float4_ lacc = {0.f, 0.f, 0.f, 0.f};
      for (int i = 0; i < 8; ++i) {
        const int ko = i * 32 + q * 8;
        short8 ah = *(const short8*)(fh + ko);
        short8 al = *(const short8*)(fl + ko);
        lacc = MFMA(ah, brh[i], lacc); lacc = MFMA(al, brh[i], lacc);
        lacc = MFMA(ah, brl[i], lacc);
      }
      for (int reg = 0; reg < 4; ++reg)
        pglds[fmt][q * 4 + reg][fkq][n16] = lacc[reg];
      __syncthreads();
      int trow = tid >> 4, tcol = tid & 15;   // 32 rows x 16 cols
      float lsum = pglds[trow >> 4][trow & 15][0][tcol] + pglds[trow >> 4][trow & 15][1][tcol] +
                   pglds[trow >> 4][trow & 15][2][tcol] + pglds[trow >> 4][trow & 15][3][tcol] +
                   fclds[tcol];
      outf[((size_t)(bq * 32 + trow) * 256 + (t - 1)) * 1024 + vbase + tcol] = lsum;
    }
    grid_barrier(bar, t + 1, 256);           // also orders glds/pglds reuse
  }

  // epilogue: logits_255 from h_255 (slot 1)
  {
    const u16* fh = hpp + (size_t)(1 * 2 + 0) * 131072 + (size_t)frow * 1024 + fkbase;
    const u16* fl = hpp + (size_t)(1 * 2 + 1) * 131072 + (size_t)frow * 1024 + fkbase;
    float4_ lacc = {0.f, 0.f, 0.f, 0.f};
    for (int i = 0; i < 8; ++i) {
      const int ko = i * 32 + q * 8;
      short8 ah = *(const short8*)(fh + ko);
      short8 al = *(const short8*)(fl + ko);
      lacc = MFMA(ah, brh[i], lacc); lacc = MFMA(al, brh[i], lacc);
      lacc = MFMA(ah, brl[i], lacc);
    }
    for (int reg = 0; reg < 4; ++reg)
      pglds[fmt][q * 4 + reg][fkq][n16] = lacc[reg];
    __syncthreads();
    int trow = tid >> 4, tcol = tid & 15;
    float lsum = pglds[trow >> 4][trow & 15][0][tcol] + pglds[trow >> 4][trow & 15][1][tcol] +
                 pglds[trow >> 4][trow & 15][2][tcol] + pglds[trow >> 4][trow & 15][3][tcol] +
                 fclds[tcol];
    outf[((size_t)(bq * 32 + trow) * 256 + 255) * 1024 + vbase + tcol] = lsum;
  }
}

// ---------------------------------------------------------------------------
extern "C" void kernel_launch(void* const* d_in, const int* in_sizes, int n_in,
                              void* d_out, int out_size, void* d_ws, size_t ws_size,
                              hipStream_t stream) {
  (void)in_sizes; (void)n_in; (void)out_size;
  const float* z    = (const float*)d_in[0];
  // d_in[1] = max_sequence_length (256) — compile-time constant here
  const float* gWih = (const float*)d_in[2];
  const float* gWhh = (const float*)d_in[3];
  const float* gbih = (const float*)d_in[4];
  const float* gbhh = (const float*)d_in[5];
  const float* lWih = (const float*)d_in[6];
  const float* lWhh = (const float*)d_in[7];
  const float* lbih = (const float*)d_in[8];
  const float* lbhh = (const float*)d_in[9];
  const float* fcW  = (const float*)d_in[10];
  const float* fcb  = (const float*)d_in[11];

  // workspace layout (total need: 1,576,960 B — proven available)
  const size_t ws_need = 4096 + 524288 + 1048576;
  if (ws_size < ws_need) return;  // diagnostic signature: absmax = max|ref|

  char* w = (char*)d_ws;
  u32* barg = (u32*)(w + 0);
  u32* barl = (u32*)(w + 256);
  u16* xpp = (u16*)(w + 4096);             // [2 slot][hi/lo][128*512]  = 512 KB
  u16* hpp = (u16*)(w + 4096 + 524288);    // [2 slot][hi/lo][128*1024] = 1 MB

  hipMemsetAsync(d_ws, 0, 4096, stream);   // zero barrier counters (ws is poisoned)

  gru_chain<<<128, 256, 0, stream>>>(z, gWih, gWhh, gbih, gbhh,
                                     (u16*)d_out, xpp, barg);
  lstm_fc_chain<<<256, 512, 0, stream>>>(lWih, lWhh, lbih, lbhh, fcW, fcb,
                                         hpp, (u16*)d_out, (float*)d_out, barl);
}

// Round 5
// 11066.486 us; speedup vs baseline: 2.1150x; 2.1150x over previous
//
#include <hip/hip_runtime.h>
#include <stdint.h>
#include <math.h>

// Decoder: autoregressive GRU (B=128,H=512,T=256) -> LSTM (L=1024) -> FC (V=1024)
// fp32 I/O. Internal math fp32; GEMMs via MFMA 16x16x32 bf16 with split-bf16
// (hi/lo) weights AND activations, 3-pass MFMA. Cross-block recurrent state
// (xpp/hpp) uses explicit sc0 sc1 (system-coherent, cache-bypassing) loads and
// stores + a fence-free grid barrier -- NO per-step L2 writeback/invalidate
// (round 4's 21-70 us/step fence cost). seq packed inside d_out as in round 4.

typedef unsigned short u16;
typedef unsigned int u32;
typedef __attribute__((ext_vector_type(8))) short short8;   // 8 bf16 = 4 VGPR
typedef __attribute__((ext_vector_type(4))) float float4_;  // MFMA acc

#define MFMA(a, b, c) __builtin_amdgcn_mfma_f32_16x16x32_bf16((a), (b), (c), 0, 0, 0)

// Coherent (LLC) 16B load, bypasses L1+L2; result usable only after WAIT8 binds it.
#define SC_LOAD(dst, ptr) \
  asm volatile("global_load_dwordx4 %0, %1, off sc0 sc1" : "=v"(dst) : "v"(ptr) : "memory")
// s_waitcnt that also "owns" 8 loaded regs so consumers can't be hoisted above it.
#define WAIT8(n, a0,a1,a2,a3,a4,a5,a6,a7) \
  asm volatile("s_waitcnt vmcnt(" #n ")" \
    : "+v"(a0),"+v"(a1),"+v"(a2),"+v"(a3),"+v"(a4),"+v"(a5),"+v"(a6),"+v"(a7) :: "memory")
// Coherent 2B store (write-through to LLC, complete when vmcnt retires).
#define SC_STORE16(ptr, val) \
  asm volatile("global_store_short %0, %1, off sc0 sc1" :: "v"(ptr), "v"((u32)(val)) : "memory")

__device__ __forceinline__ float bf2f(u16 u) {
  union { u32 i; float f; } v; v.i = ((u32)u) << 16; return v.f;
}
__device__ __forceinline__ u16 f2bf(float f) {
  union { float f; u32 i; } v; v.f = f;
  u32 x = v.i;
  return (u16)((x + 0x7fffu + ((x >> 16) & 1u)) >> 16);  // RNE, finite inputs only
}
__device__ __forceinline__ void split2(float w, u16& h, u16& l) {
  h = f2bf(w); l = f2bf(w - bf2f(h));
}
__device__ __forceinline__ float sigm(float x) { return 1.0f / (1.0f + expf(-x)); }

__device__ __forceinline__ void frag_from_f32(const float* p, short8& hi, short8& lo) {
  short8 h, l;
#pragma unroll
  for (int j = 0; j < 8; ++j) {
    u16 a, b; split2(p[j], a, b);
    h[j] = (short)a; l[j] = (short)b;
  }
  hi = h; lo = l;
}

// Fence-free grid barrier: payload is sc-coherent at vmcnt retirement, so we
// drain vmcnt in every lane, block-barrier, then one relaxed arrive + spin.
// No buffer_wbl2 / buffer_inv -- L2 contents (seq, weights) stay warm.
__device__ __forceinline__ void grid_barrier(u32* bar, u32 gen, u32 nblk) {
  asm volatile("s_waitcnt vmcnt(0)" ::: "memory");
  __syncthreads();
  if (threadIdx.x == 0) {
    atomicAdd(bar, 1u);                      // device-scope, coherence point
    const u32 target = gen * nblk;
    while (__hip_atomic_load(bar, __ATOMIC_RELAXED, __HIP_MEMORY_SCOPE_AGENT) < target)
      __builtin_amdgcn_s_sleep(2);
  }
  __syncthreads();
}

// ---------------------------------------------------------------------------
// Kernel 1: persistent GRU chain. 128 blocks x 256 threads. Same layout/math
// as round 4; xpp access converted to sc loads/stores.
// ---------------------------------------------------------------------------
__global__ __launch_bounds__(256)
void gru_chain(const float* __restrict__ z,
               const float* __restrict__ Wih, const float* __restrict__ Whh,
               const float* __restrict__ bih, const float* __restrict__ bhh,
               u16* outu, u16* __restrict__ xpp, u32* bar) {
  __shared__ __align__(16) u16 wh_lds[48 * 520];
  __shared__ __align__(16) u16 wl_lds[48 * 520];
  __shared__ float blds[32];

  const int tid = threadIdx.x;
  const int wg = blockIdx.x;
  const int grp = wg & 63;
  const int mhalf = wg >> 6;
  const int jb = grp * 8;

  for (int idx = tid; idx < 48 * 512; idx += 256) {
    int row = idx >> 9, k = idx & 511;
    int t3 = row >> 4, n = row & 15;
    int grow = t3 * 512 + jb + (n & 7);
    float w = ((n < 8) ? Wih : Whh)[(size_t)grow * 512 + k];
    u16 h, l; split2(w, h, l);
    wh_lds[row * 520 + k] = h;
    wl_lds[row * 520 + k] = l;
  }
  if (tid < 8) {
    blds[tid]      = bih[jb + tid] + bhh[jb + tid];
    blds[8 + tid]  = bih[512 + jb + tid] + bhh[512 + jb + tid];
    blds[16 + tid] = bih[1024 + jb + tid];
    blds[24 + tid] = bhh[1024 + jb + tid];
  }
  __syncthreads();

  const int lane = tid & 63, wv = tid >> 6;
  const int n16 = lane & 15, q = lane >> 4;
  const int j8 = n16 & 7;
  const int mrow = mhalf * 64 + wv * 16 + n16;
  const int orow0 = mhalf * 64 + wv * 16 + q * 4;
  const bool act = (n16 < 8);
  const int col = jb + j8;
  const int qo = q * 8;

  float x_own[4];

  // ---- step 1: x1 = GRU(x=0, h=z); A = z hi/lo (normal cached loads) ----
  {
    float4_ acc0 = {0.f, 0.f, 0.f, 0.f}, acc1 = acc0, acc2 = acc0;
    for (int ki = 0; ki < 16; ++ki) {
      const int ko = ki * 32 + qo;
      short8 ah, al;
      frag_from_f32(z + (size_t)mrow * 512 + ko, ah, al);
      short8 b0h = *(const short8*)(wh_lds + (0 * 16 + n16) * 520 + ko);
      short8 b1h = *(const short8*)(wh_lds + (1 * 16 + n16) * 520 + ko);
      short8 b2h = *(const short8*)(wh_lds + (2 * 16 + n16) * 520 + ko);
      short8 b0l = *(const short8*)(wl_lds + (0 * 16 + n16) * 520 + ko);
      short8 b1l = *(const short8*)(wl_lds + (1 * 16 + n16) * 520 + ko);
      short8 b2l = *(const short8*)(wl_lds + (2 * 16 + n16) * 520 + ko);
      acc0 = MFMA(ah, b0h, acc0); acc0 = MFMA(al, b0h, acc0); acc0 = MFMA(ah, b0l, acc0);
      acc1 = MFMA(ah, b1h, acc1); acc1 = MFMA(al, b1h, acc1); acc1 = MFMA(ah, b1l, acc1);
      acc2 = MFMA(ah, b2h, acc2); acc2 = MFMA(al, b2h, acc2); acc2 = MFMA(ah, b2l, acc2);
    }
    for (int reg = 0; reg < 4; ++reg) {
      float pr = __shfl_xor(acc0[reg], 8);
      float pz = __shfl_xor(acc1[reg], 8);
      float pn = __shfl_xor(acc2[reg], 8);
      float r  = sigm(pr + blds[j8]);
      float zg = sigm(pz + blds[8 + j8]);
      float nn = tanhf(blds[16 + j8] + r * (pn + blds[24 + j8]));
      float hv = act ? z[(size_t)(orow0 + reg) * 512 + col] : 0.f;
      float xn = (1.f - zg) * nn + zg * hv;
      x_own[reg] = xn;
      if (act) {
        size_t po = (size_t)(orow0 + reg) * 512 + col;
        u16 h, l; split2(xn, h, l);
        SC_STORE16(xpp + (size_t)2 * 65536 + po, h);   // slot 1 hi
        SC_STORE16(xpp + (size_t)3 * 65536 + po, l);   // slot 1 lo
        float rl = fmaxf(xn, 0.f);
        u16 rh, rlo; split2(rl, rh, rlo);
        size_t so = ((size_t)(orow0 + reg) * 256 + 1) * 2048;
        outu[so + col] = rh;
        outu[so + 512 + col] = rlo;
      }
    }
  }
  grid_barrier(bar, 1, 128);

  // ---- steps 2..255: A = x_{t-1} hi/lo via sc loads (issue-all, wait-all) ----
  for (int t = 2; t < 256; ++t) {
    const int sr = (t - 1) & 1, sw = t & 1;
    const u16* xh = xpp + (size_t)(sr * 2 + 0) * 65536 + (size_t)mrow * 512;
    const u16* xl = xpp + (size_t)(sr * 2 + 1) * 65536 + (size_t)mrow * 512;
    short8 bufh[16], bufl[16];
#pragma unroll
    for (int ki = 0; ki < 16; ++ki) {
      SC_LOAD(bufh[ki], xh + ki * 32 + qo);
      SC_LOAD(bufl[ki], xl + ki * 32 + qo);
    }
    WAIT8(0, bufh[0], bufh[1], bufh[2], bufh[3], bufh[4], bufh[5], bufh[6], bufh[7]);
    WAIT8(0, bufh[8], bufh[9], bufh[10], bufh[11], bufh[12], bufh[13], bufh[14], bufh[15]);
    WAIT8(0, bufl[0], bufl[1], bufl[2], bufl[3], bufl[4], bufl[5], bufl[6], bufl[7]);
    WAIT8(0, bufl[8], bufl[9], bufl[10], bufl[11], bufl[12], bufl[13], bufl[14], bufl[15]);

    float4_ acc0 = {0.f, 0.f, 0.f, 0.f}, acc1 = acc0, acc2 = acc0;
#pragma unroll
    for (int ki = 0; ki < 16; ++ki) {
      const int ko = ki * 32 + qo;
      short8 b0h = *(const short8*)(wh_lds + (0 * 16 + n16) * 520 + ko);
      short8 b1h = *(const short8*)(wh_lds + (1 * 16 + n16) * 520 + ko);
      short8 b2h = *(const short8*)(wh_lds + (2 * 16 + n16) * 520 + ko);
      short8 b0l = *(const short8*)(wl_lds + (0 * 16 + n16) * 520 + ko);
      short8 b1l = *(const short8*)(wl_lds + (1 * 16 + n16) * 520 + ko);
      short8 b2l = *(const short8*)(wl_lds + (2 * 16 + n16) * 520 + ko);
      acc0 = MFMA(bufh[ki], b0h, acc0); acc0 = MFMA(bufl[ki], b0h, acc0); acc0 = MFMA(bufh[ki], b0l, acc0);
      acc1 = MFMA(bufh[ki], b1h, acc1); acc1 = MFMA(bufl[ki], b1h, acc1); acc1 = MFMA(bufh[ki], b1l, acc1);
      acc2 = MFMA(bufh[ki], b2h, acc2); acc2 = MFMA(bufl[ki], b2h, acc2); acc2 = MFMA(bufh[ki], b2l, acc2);
    }
    for (int reg = 0; reg < 4; ++reg) {
      float ar = acc0[reg], az = acc1[reg], an = acc2[reg];
      float pr = __shfl_xor(ar, 8), pz = __shfl_xor(az, 8), pn = __shfl_xor(an, 8);
      float r  = sigm(ar + pr + blds[j8]);
      float zg = sigm(az + pz + blds[8 + j8]);
      float nn = tanhf(an + blds[16 + j8] + r * (pn + blds[24 + j8]));
      float xn = (1.f - zg) * nn + zg * x_own[reg];
      x_own[reg] = xn;
      if (act) {
        size_t po = (size_t)(orow0 + reg) * 512 + col;
        u16 h, l; split2(xn, h, l);
        SC_STORE16(xpp + (size_t)(sw * 2 + 0) * 65536 + po, h);
        SC_STORE16(xpp + (size_t)(sw * 2 + 1) * 65536 + po, l);
        float rl = fmaxf(xn, 0.f);
        u16 rh, rlo; split2(rl, rh, rlo);
        size_t so = ((size_t)(orow0 + reg) * 256 + (size_t)t) * 2048;
        outu[so + col] = rh;
        outu[so + 512 + col] = rlo;
      }
    }
    if (t < 255) grid_barrier(bar, t, 128);
  }
}

// ---------------------------------------------------------------------------
// Kernel 2: persistent LSTM chain with fused FC. 256 blocks x 512 threads.
// Same layout/math as round 4; hpp access converted to sc loads/stores with a
// double-buffered 8-ki chunk pipeline (vmcnt(16) steady state).
// ---------------------------------------------------------------------------
__global__ __launch_bounds__(512)
void lstm_fc_chain(const float* __restrict__ Wih, const float* __restrict__ Whh,
                   const float* __restrict__ bih, const float* __restrict__ bhh,
                   const float* __restrict__ fcW, const float* __restrict__ fcb,
                   u16* __restrict__ hpp, u16* outu, float* outf, u32* bar) {
  __shared__ __align__(16) u16 whh_hi[16 * 1032];
  __shared__ __align__(16) u16 whh_lo[16 * 1032];
  __shared__ __align__(16) u16 wih_hi[16 * 520];
  __shared__ __align__(16) u16 wih_lo[16 * 520];
  __shared__ float glds[128][17];
  __shared__ float pglds[2][16][4][16];
  __shared__ float bclds[16];
  __shared__ float fclds[16];

  const int tid = threadIdx.x;
  const int s = blockIdx.x;
  const int colbase = s * 4;
  const int vt = s & 63, bq = s >> 6;
  const int vbase = vt * 16;

  for (int idx = tid; idx < 16 * 1024; idx += 512) {
    int row = idx >> 10, k = idx & 1023;
    int gate = row >> 2, cc = row & 3;
    float w = Whh[(size_t)(gate * 1024 + colbase + cc) * 1024 + k];
    u16 h, l; split2(w, h, l);
    whh_hi[row * 1032 + k] = h;
    whh_lo[row * 1032 + k] = l;
  }
  for (int idx = tid; idx < 16 * 512; idx += 512) {
    int row = idx >> 9, k = idx & 511;
    int gate = row >> 2, cc = row & 3;
    float w = Wih[(size_t)(gate * 1024 + colbase + cc) * 512 + k];
    u16 h, l; split2(w, h, l);
    wih_hi[row * 520 + k] = h;
    wih_lo[row * 520 + k] = l;
  }
  if (tid < 16) {
    int gate = tid >> 2, cc = tid & 3;
    int wcol = gate * 1024 + colbase + cc;
    bclds[tid] = bih[wcol] + bhh[wcol];
    fclds[tid] = fcb[vbase + tid];
  }
  __syncthreads();

  const int lane = tid & 63, wv = tid >> 6;
  const int n16 = lane & 15, q = lane >> 4;
  const int qo = q * 8;
  const int arow = wv * 16 + n16;
  const int myrow = tid >> 2, mycol = tid & 3;
  const int fmt = wv & 1, fkq = wv >> 1;
  const int frow = bq * 32 + fmt * 16 + n16;
  const int fkbase = fkq * 256;

  short8 brh[8], brl[8];
  for (int i = 0; i < 8; ++i)
    frag_from_f32(fcW + (size_t)(vbase + n16) * 1024 + fkbase + i * 32 + qo,
                  brh[i], brl[i]);

  float c = 0.f;

  // t = 0: preacts are just biases
  {
    float pi = bclds[mycol], pg = bclds[8 + mycol], po = bclds[12 + mycol];
    c = sigm(pi) * tanhf(pg);
    float h = sigm(po) * tanhf(c);
    size_t off = (size_t)myrow * 1024 + colbase + mycol;
    u16 hh, hl; split2(h, hh, hl);
    SC_STORE16(hpp + off, hh);
    SC_STORE16(hpp + 131072 + off, hl);
  }
  grid_barrier(bar, 1, 256);

  for (int t = 1; t < 256; ++t) {
    const int sr = (t - 1) & 1, sw = t & 1;
    const u16* ph = hpp + (size_t)(sr * 2 + 0) * 131072 + (size_t)arow * 1024;
    const u16* pl = hpp + (size_t)(sr * 2 + 1) * 131072 + (size_t)arow * 1024;
    float4_ acc = {0.f, 0.f, 0.f, 0.f};

    // recurrent part, K=1024: 4 chunks of 8 ki, double-buffered sc loads
    {
      short8 hb[2][8], lb[2][8];
#pragma unroll
      for (int j = 0; j < 8; ++j) {
        SC_LOAD(hb[0][j], ph + j * 32 + qo);
        SC_LOAD(lb[0][j], pl + j * 32 + qo);
      }
#pragma unroll
      for (int ch = 0; ch < 4; ++ch) {
        const int cur = ch & 1, nxt = cur ^ 1;
        if (ch < 3) {
#pragma unroll
          for (int j = 0; j < 8; ++j) {
            SC_LOAD(hb[nxt][j], ph + ((ch + 1) * 8 + j) * 32 + qo);
            SC_LOAD(lb[nxt][j], pl + ((ch + 1) * 8 + j) * 32 + qo);
          }
          WAIT8(16, hb[cur][0], hb[cur][1], hb[cur][2], hb[cur][3],
                    hb[cur][4], hb[cur][5], hb[cur][6], hb[cur][7]);
          WAIT8(16, lb[cur][0], lb[cur][1], lb[cur][2], lb[cur][3],
                    lb[cur][4], lb[cur][5], lb[cur][6], lb[cur][7]);
        } else {
          WAIT8(0, hb[cur][0], hb[cur][1], hb[cur][2], hb[cur][3],
                   hb[cur][4], hb[cur][5], hb[cur][6], hb[cur][7]);
          WAIT8(0, lb[cur][0], lb[cur][1], lb[cur][2], lb[cur][3],
                   lb[cur][4], lb[cur][5], lb[cur][6], lb[cur][7]);
        }
#pragma unroll
        for (int j = 0; j < 8; ++j) {
          const int ko = (ch * 8 + j) * 32 + qo;
          short8 bh = *(const short8*)(whh_hi + n16 * 1032 + ko);
          short8 bl = *(const short8*)(whh_lo + n16 * 1032 + ko);
          acc = MFMA(hb[cur][j], bh, acc);
          acc = MFMA(lb[cur][j], bh, acc);
          acc = MFMA(hb[cur][j], bl, acc);
        }
      }
    }
    // input part, K=512: seq planes from outu (normal cached loads, L2-warm)
    {
      const u16* sq = outu + ((size_t)arow * 256 + t) * 2048;
      for (int ki = 0; ki < 16; ++ki) {
        const int ko = ki * 32 + qo;
        short8 sh = *(const short8*)(sq + ko);
        short8 sl = *(const short8*)(sq + 512 + ko);
        short8 bh = *(const short8*)(wih_hi + n16 * 520 + ko);
        short8 bl = *(const short8*)(wih_lo + n16 * 520 + ko);
        acc = MFMA(sh, bh, acc); acc = MFMA(sl, bh, acc); acc = MFMA(sh, bl, acc);
      }
    }
    for (int reg = 0; reg < 4; ++reg)
      glds[wv * 16 + q * 4 + reg][n16] = acc[reg];
    __syncthreads();
    {
      float pi = glds[myrow][mycol]      + bclds[mycol];
      float pf = glds[myrow][4 + mycol]  + bclds[4 + mycol];
      float pg = glds[myrow][8 + mycol]  + bclds[8 + mycol];
      float po = glds[myrow][12 + mycol] + bclds[12 + mycol];
      c = sigm(pf) * c + sigm(pi) * tanhf(pg);
      float h = sigm(po) * tanhf(c);
      size_t off = (size_t)myrow * 1024 + colbase + mycol;
      u16 hh, hl; split2(h, hh, hl);
      SC_STORE16(hpp + (size_t)(sw * 2 + 0) * 131072 + off, hh);
      SC_STORE16(hpp + (size_t)(sw * 2 + 1) * 131072 + off, hl);
    }

    // fused FC: logits_{t-1} from h_{t-1} (sc loads, issue-all/wait-all)
    {
      const u16* fh = hpp + (size_t)(sr * 2 + 0) * 131072 + (size_t)frow * 1024 + fkbase;
      const u16* fl = hpp + (size_t)(sr * 2 + 1) * 131072 + (size_t)frow * 1024 + fkbase;
      short8 fhb[8], flb[8];
#pragma unroll
      for (int i = 0; i < 8; ++i) {
        SC_LOAD(fhb[i], fh + i * 32 + qo);
        SC_LOAD(flb[i], fl + i * 32 + qo);
      }
      WAIT8(0, fhb[0], fhb[1], fhb[2], fhb[3], fhb[4], fhb[5], fhb[6], fhb[7]);
      WAIT8(0, flb[0], flb[1], flb[2], flb[3], flb[4], flb[5], flb[6], flb[7]);
      float4_ lacc = {0.f, 0.f, 0.f, 0.f};
#pragma unroll
      for (int i = 0; i < 8; ++i) {
        lacc = MFMA(fhb[i], brh[i], lacc);
        lacc = MFMA(flb[i], brh[i], lacc);
        lacc = MFMA(fhb[i], brl[i], lacc);
      }
      for (int reg = 0; reg < 4; ++reg)
        pglds[fmt][q * 4 + reg][fkq][n16] = lacc[reg];
      __syncthreads();
      int trow = tid >> 4, tcol = tid & 15;
      float lsum = pglds[trow >> 4][trow & 15][0][tcol] + pglds[trow >> 4][trow & 15][1][tcol] +
                   pglds[trow >> 4][trow & 15][2][tcol] + pglds[trow >> 4][trow & 15][3][tcol] +
                   fclds[tcol];
      outf[((size_t)(bq * 32 + trow) * 256 + (t - 1)) * 1024 + vbase + tcol] = lsum;
    }
    grid_barrier(bar, t + 1, 256);
  }

  // epilogue: logits_255 from h_255 (slot 1)
  {
    const u16* fh = hpp + (size_t)(1 * 2 + 0) * 131072 + (size_t)frow * 1024 + fkbase;
    const u16* fl = hpp + (size_t)(1 * 2 + 1) * 131072 + (size_t)frow * 1024 + fkbase;
    short8 fhb[8], flb[8];
#pragma unroll
    for (int i = 0; i < 8; ++i) {
      SC_LOAD(fhb[i], fh + i * 32 + qo);
      SC_LOAD(flb[i], fl + i * 32 + qo);
    }
    WAIT8(0, fhb[0], fhb[1], fhb[2], fhb[3], fhb[4], fhb[5], fhb[6], fhb[7]);
    WAIT8(0, flb[0], flb[1], flb[2], flb[3], flb[4], flb[5], flb[6], flb[7]);
    float4_ lacc = {0.f, 0.f, 0.f, 0.f};
#pragma unroll
    for (int i = 0; i < 8; ++i) {
      lacc = MFMA(fhb[i], brh[i], lacc);
      lacc = MFMA(flb[i], brh[i], lacc);
      lacc = MFMA(fhb[i], brl[i], lacc);
    }
    for (int reg = 0; reg < 4; ++reg)
      pglds[fmt][q * 4 + reg][fkq][n16] = lacc[reg];
    __syncthreads();
    int trow = tid >> 4, tcol = tid & 15;
    float lsum = pglds[trow >> 4][trow & 15][0][tcol] + pglds[trow >> 4][trow & 15][1][tcol] +
                 pglds[trow >> 4][trow & 15][2][tcol] + pglds[trow >> 4][trow & 15][3][tcol] +
                 fclds[tcol];
    outf[((size_t)(bq * 32 + trow) * 256 + 255) * 1024 + vbase + tcol] = lsum;
  }
}

// ---------------------------------------------------------------------------
extern "C" void kernel_launch(void* const* d_in, const int* in_sizes, int n_in,
                              void* d_out, int out_size, void* d_ws, size_t ws_size,
                              hipStream_t stream) {
  (void)in_sizes; (void)n_in; (void)out_size;
  const float* z    = (const float*)d_in[0];
  const float* gWih = (const float*)d_in[2];
  const float* gWhh = (const float*)d_in[3];
  const float* gbih = (const float*)d_in[4];
  const float* gbhh = (const float*)d_in[5];
  const float* lWih = (const float*)d_in[6];
  const float* lWhh = (const float*)d_in[7];
  const float* lbih = (const float*)d_in[8];
  const float* lbhh = (const float*)d_in[9];
  const float* fcW  = (const float*)d_in[10];
  const float* fcb  = (const float*)d_in[11];

  const size_t ws_need = 4096 + 524288 + 1048576;
  if (ws_size < ws_need) return;

  char* w = (char*)d_ws;
  u32* barg = (u32*)(w + 0);
  u32* barl = (u32*)(w + 256);
  u16* xpp = (u16*)(w + 4096);             // [2 slot][hi/lo][128*512]  = 512 KB
  u16* hpp = (u16*)(w + 4096 + 524288);    // [2 slot][hi/lo][128*1024] = 1 MB

  hipMemsetAsync(d_ws, 0, 4096, stream);   // zero barrier counters

  gru_chain<<<128, 256, 0, stream>>>(z, gWih, gWhh, gbih, gbhh,
                                     (u16*)d_out, xpp, barg);
  lstm_fc_chain<<<256, 512, 0, stream>>>(lWih, lWhh, lbih, lbhh, fcW, fcb,
                                         hpp, (u16*)d_out, (float*)d_out, barl);
}